// Round 12
// baseline (302.773 us; speedup 1.0000x reference)
//
#include <hip/hip_runtime.h>
#include <hip/hip_bf16.h>
#include <stdint.h>

typedef __attribute__((ext_vector_type(8))) short short8;
typedef __attribute__((ext_vector_type(4))) float f32x4;

constexpr int Hc = 128, Wc = 128, HWc = Hc * Wc;
constexpr int Cin = 128, Cout = 128;
constexpr int OffC = 18, OffIn = 64;

__device__ __forceinline__ float bf2f(unsigned short u) {
    return __builtin_bit_cast(float, (unsigned)u << 16);
}
__device__ __forceinline__ unsigned short f2bf(float f) {
    unsigned u = __builtin_bit_cast(unsigned, f);
    return (unsigned short)((u + 0x7FFFu + ((u >> 16) & 1u)) >> 16);
}

// ---- 1x1 offset conv: off [B,64,HW] x w_off [18,64] + b_off -> offset [B,18,HW]
__global__ void k_offconv(const float* __restrict__ off, const float* __restrict__ w_off,
                          const float* __restrict__ b_off, float* __restrict__ offset) {
    __shared__ float wsm[OffC * OffIn];
    __shared__ float bsm[OffC];
    int tid = threadIdx.x;
    for (int i = tid; i < OffC * OffIn; i += 256) wsm[i] = w_off[i];
    if (tid < OffC) bsm[tid] = b_off[tid];
    __syncthreads();
    int g = blockIdx.x * 256 + tid;            // one pixel per thread
    int b = g >> 14, hw = g & (HWc - 1);
    const float* offb = off + b * OffIn * HWc + hw;
    float acc[OffC];
#pragma unroll
    for (int o = 0; o < OffC; ++o) acc[o] = bsm[o];
    for (int c = 0; c < OffIn; ++c) {
        float v = offb[c << 14];
#pragma unroll
        for (int o = 0; o < OffC; ++o) acc[o] += wsm[o * OffIn + c] * v;
    }
    float* outb = offset + b * OffC * HWc + hw;
#pragma unroll
    for (int o = 0; o < OffC; ++o) outb[o << 14] = acc[o];
}

// ---- x [B,C,H,W] fp32 -> x_t [B,H,W,C] bf16 (channels-last for coalesced gather)
__global__ void k_xpose(const float* __restrict__ x, unsigned short* __restrict__ xt) {
    __shared__ float tile[128][65];
    int blk = blockIdx.x;
    int b = blk >> 8;
    int hw0 = (blk & 255) << 6;
    const float* xb = x + b * Cin * HWc;
    int tid = threadIdx.x;
#pragma unroll
    for (int k = 0; k < 32; ++k) {
        int e = tid + k * 256;
        int c = e >> 6, p = e & 63;
        tile[c][p] = xb[(c << 14) + hw0 + p];
    }
    __syncthreads();
    unsigned short* xtb = xt + ((b << 14) + hw0) * Cin;
#pragma unroll
    for (int k = 0; k < 16; ++k) {
        int e = (tid + k * 256) * 2;
        int p = e >> 7, c = e & 127;
        unsigned lo = f2bf(tile[c][p]);
        unsigned hi = f2bf(tile[c + 1][p]);
        *(unsigned*)(xtb + e) = lo | (hi << 16);
    }
}

// ---- w_def [O,C,3,3] fp32 -> Wt [kk][O][C] bf16
__global__ void k_wprep(const float* __restrict__ wd, unsigned short* __restrict__ wt) {
    int i = blockIdx.x * 256 + threadIdx.x;
    int kk = i >> 14, o = (i >> 7) & 127, c = i & 127;
    wt[i] = f2bf(wd[((o << 7) + c) * 9 + kk]);
}

// ---- main: 1024 blocks x 256 threads, 4 independent waves per block.
// One wave = 16 pixels (1 B-tile) x 128 outputs (8 A-tiles). Zero LDS,
// zero barriers. 4096 waves -> 16 waves/CU for latency hiding.
__global__ __launch_bounds__(256, 4)
void k_deform(const unsigned short* __restrict__ xt, const float* __restrict__ offset,
              const unsigned short* __restrict__ wt, float* __restrict__ out) {
    int tid = threadIdx.x;
    int lane = tid & 63, wave = tid >> 6;
    int bid = blockIdx.x;
    int swz = (bid & 7) * 128 + (bid >> 3);    // XCD-bijective (1024 = 8*128)
    int b = swz >> 8;                          // 256 blocks per batch
    int hw0 = (swz & 255) << 6;                // 64-px block window
    int p0 = hw0 + (wave << 4) + (lane & 15);  // this lane's pixel
    int cg = lane >> 4;                        // k-group 0..3

    const unsigned short* xb = xt + ((size_t)b << 21);
    const float* offp = offset + (size_t)b * (OffC * HWc);

    int h0 = p0 >> 7, w0 = p0 & 127;

    f32x4 acc[8];
#pragma unroll
    for (int i = 0; i < 8; ++i) acc[i] = (f32x4){0.f, 0.f, 0.f, 0.f};

    auto cparm = [&](int tap, float dy, float dx, float* cw, int* cb) {
        float ys = (float)(h0 - 1 + tap / 3) + dy;
        float xs = (float)(w0 - 1 + tap % 3) + dx;
        float y0f = floorf(ys), x0f = floorf(xs);
        float ly = ys - y0f, lx = xs - x0f;
        int y0 = (int)y0f, x0 = (int)x0f;
#pragma unroll
        for (int cr = 0; cr < 4; ++cr) {
            int yi = y0 + (cr >> 1), xi = x0 + (cr & 1);
            bool valid = (yi >= 0) && (yi < Hc) && (xi >= 0) && (xi < Wc);
            float wy = (cr >> 1) ? ly : 1.0f - ly;
            float wx = (cr & 1) ? lx : 1.0f - lx;
            int yc = yi < 0 ? 0 : (yi > Hc - 1 ? Hc - 1 : yi);
            int xc = xi < 0 ? 0 : (xi > Wc - 1 ? Wc - 1 : xi);
            cw[cr] = valid ? wy * wx : 0.0f;
            cb[cr] = ((yc << 7) + xc) << 7;    // element offset within batch slice
        }
    };

    // blend 4 corner short8's into one bf16 B-fragment (hardware cvt_pk, RNE)
    auto blend = [&](const short8* r, const float* cw) -> short8 {
        union { unsigned u[4]; short8 s; } pk;
#pragma unroll
        for (int j = 0; j < 4; ++j) {
            float va = cw[0] * bf2f((unsigned short)r[0][2 * j])
                     + cw[1] * bf2f((unsigned short)r[1][2 * j])
                     + cw[2] * bf2f((unsigned short)r[2][2 * j])
                     + cw[3] * bf2f((unsigned short)r[3][2 * j]);
            float vb = cw[0] * bf2f((unsigned short)r[0][2 * j + 1])
                     + cw[1] * bf2f((unsigned short)r[1][2 * j + 1])
                     + cw[2] * bf2f((unsigned short)r[2][2 * j + 1])
                     + cw[3] * bf2f((unsigned short)r[3][2 * j + 1]);
            __hip_bfloat162 h2 = __float22bfloat162_rn(make_float2(va, vb));
            unsigned r32;
            __builtin_memcpy(&r32, &h2, 4);    // bit_cast rejected: not trivially copyable
            pk.u[j] = r32;
        }
        return pk.s;
    };

    float cw0[4]; int cb0[4];
    float dy0 = offp[p0], dx0 = offp[(1 << 14) + p0];

    for (int t = 0; t < 9; ++t) {
        cparm(t, dy0, dx0, cw0, cb0);
        if (t < 8) {   // prefetch next tap's offsets (L1-hot)
            dy0 = offp[((2 * t + 2) << 14) + p0];
            dx0 = offp[((2 * t + 3) << 14) + p0];
        }
        const unsigned short* wtap = wt + (t << 14);
#pragma unroll
        for (int ks = 0; ks < 4; ++ks) {
            int kc = (ks << 5) + (cg << 3);
            short8 r0[4];
#pragma unroll
            for (int cr = 0; cr < 4; ++cr)
                r0[cr] = *(const short8*)(xb + cb0[cr] + kc);
            short8 A[8];
#pragma unroll
            for (int ot = 0; ot < 8; ++ot)
                A[ot] = *(const short8*)(wtap + ((ot << 4) + (lane & 15)) * 128 + kc);
            short8 bf0 = blend(r0, cw0);
#pragma unroll
            for (int ot = 0; ot < 8; ++ot)
                acc[ot] = __builtin_amdgcn_mfma_f32_16x16x32_bf16(A[ot], bf0, acc[ot], 0, 0, 0);
        }
    }

    // epilogue: ReLU + fp32 store. D: col=lane&15 (pixel), row=(lane>>4)*4+j (o)
#pragma unroll
    for (int ot = 0; ot < 8; ++ot)
#pragma unroll
        for (int j = 0; j < 4; ++j) {
            int o = (ot << 4) + ((lane >> 4) << 2) + j;
            float v = acc[ot][j];
            out[(((size_t)(b << 7) + o) << 14) + p0] = v > 0.f ? v : 0.f;
        }
}

extern "C" void kernel_launch(void* const* d_in, const int* in_sizes, int n_in,
                              void* d_out, int out_size, void* d_ws, size_t ws_size,
                              hipStream_t stream) {
    const float* x     = (const float*)d_in[0];
    const float* off   = (const float*)d_in[1];
    const float* w_off = (const float*)d_in[2];
    const float* b_off = (const float*)d_in[3];
    const float* w_def = (const float*)d_in[4];
    float* out = (float*)d_out;

    char* ws = (char*)d_ws;
    float* offset      = (float*)ws;                                  // 4,718,592 B
    unsigned short* xt = (unsigned short*)(ws + 4718592);             // 16,777,216 B
    unsigned short* wt = (unsigned short*)(ws + 4718592 + 16777216);  // 294,912 B

    hipLaunchKernelGGL(k_offconv, dim3(256),  dim3(256), 0, stream, off, w_off, b_off, offset);
    hipLaunchKernelGGL(k_xpose,   dim3(1024), dim3(256), 0, stream, x, xt);
    hipLaunchKernelGGL(k_wprep,   dim3(576),  dim3(256), 0, stream, w_def, wt);
    hipLaunchKernelGGL(k_deform,  dim3(1024), dim3(256), 0, stream, xt, offset, wt, out);
}

// Round 14
// 198.657 us; speedup vs baseline: 1.5241x; 1.5241x over previous
//
#include <hip/hip_runtime.h>
#include <stdint.h>

typedef __attribute__((ext_vector_type(8))) short short8;
typedef __attribute__((ext_vector_type(4))) float f32x4;

constexpr int Hc = 128, Wc = 128, HWc = Hc * Wc;
constexpr int OffC = 18, OffIn = 64;

__device__ __forceinline__ float bf2f(unsigned short u) {
    return __builtin_bit_cast(float, (unsigned)u << 16);
}
__device__ __forceinline__ unsigned short f2bf(float f) {
    unsigned u = __builtin_bit_cast(unsigned, f);
    return (unsigned short)((u + 0x7FFFu + ((u >> 16) & 1u)) >> 16);
}

// ---- 1x1 offset conv: off [B,64,HW] x w_off [18,64] + b_off -> offset [B,18,HW]
__global__ void k_offconv(const float* __restrict__ off, const float* __restrict__ w_off,
                          const float* __restrict__ b_off, float* __restrict__ offset) {
    __shared__ float wsm[OffC * OffIn];
    __shared__ float bsm[OffC];
    int tid = threadIdx.x;
    for (int i = tid; i < OffC * OffIn; i += 256) wsm[i] = w_off[i];
    if (tid < OffC) bsm[tid] = b_off[tid];
    __syncthreads();
    int g = blockIdx.x * 256 + tid;
    int b = g >> 14, hw = g & (HWc - 1);
    const float* offb = off + b * OffIn * HWc + hw;
    float acc[OffC];
#pragma unroll
    for (int o = 0; o < OffC; ++o) acc[o] = bsm[o];
    for (int c = 0; c < OffIn; ++c) {
        float v = offb[c << 14];
#pragma unroll
        for (int o = 0; o < OffC; ++o) acc[o] += wsm[o * OffIn + c] * v;
    }
    float* outb = offset + b * OffC * HWc + hw;
#pragma unroll
    for (int o = 0; o < OffC; ++o) outb[o << 14] = acc[o];
}

// ---- x [B,C,H,W] fp32 -> x_t [B,H,W,C] bf16 (channels-last for coalesced gather)
__global__ void k_xpose(const float* __restrict__ x, unsigned short* __restrict__ xt) {
    __shared__ float tile[128][65];
    int blk = blockIdx.x;
    int b = blk >> 8;
    int hw0 = (blk & 255) << 6;
    const float* xb = x + b * 128 * HWc;
    int tid = threadIdx.x;
#pragma unroll
    for (int k = 0; k < 32; ++k) {
        int e = tid + k * 256;
        int c = e >> 6, p = e & 63;
        tile[c][p] = xb[(c << 14) + hw0 + p];
    }
    __syncthreads();
    unsigned short* xtb = xt + ((b << 14) + hw0) * 128;
#pragma unroll
    for (int k = 0; k < 16; ++k) {
        int e = (tid + k * 256) * 2;
        int p = e >> 7, c = e & 127;
        unsigned lo = f2bf(tile[c][p]);
        unsigned hi = f2bf(tile[c + 1][p]);
        *(unsigned*)(xtb + e) = lo | (hi << 16);
    }
}

// ---- w_def [O,C,3,3] fp32 -> wtf fragment order:
// element index i = ((kstep*16 + ot*2 + ks)*64 + lane)*8 + j
// o = ot*16 + (lane&15); k = kstep*64 + ks*32 + (lane>>4)*8 + j; tap = k>>7; c = k&127
__global__ void k_wprep(const float* __restrict__ wd, unsigned short* __restrict__ wtf) {
    int i = blockIdx.x * 256 + threadIdx.x;       // 576 blocks -> 147456 elems
    int j = i & 7, lane = (i >> 3) & 63, ks = (i >> 9) & 1, ot = (i >> 10) & 7, kstep = i >> 13;
    int o = (ot << 4) + (lane & 15);
    int k = (kstep << 6) + (ks << 5) + ((lane >> 4) << 3) + j;
    int tap = k >> 7, c = k & 127;
    wtf[i] = f2bf(wd[(o * 128 + c) * 9 + tap]);
}

// ---- main: 1024 blocks x 512 threads (8 waves), 1 block/CU.
// Phase 1: coalesced gather of all 9 taps -> full K=1152 v-panel in LDS
//          (64 px rows, 2320 B pitch for conflict-free GEMM reads).
// Phase 2: barrier-free 18-step GEMM; A from fragment-ordered wtf (1 KB
//          coalesced wave-loads, L1/L2-hot); B from LDS panel.
__global__ __launch_bounds__(512, 1)
void k_deform(const unsigned short* __restrict__ xt, const float* __restrict__ offset,
              const unsigned short* __restrict__ wtf, float* __restrict__ out) {
    __shared__ unsigned short vt[64 * 1160];      // 64 rows x 2320 B = 148480 B
    __shared__ float cwL[4][64];
    __shared__ int   cbL[4][64];

    int tid = threadIdx.x;
    int bid = blockIdx.x;
    int swz = (bid & 7) * 128 + (bid >> 3);       // XCD-bijective (1024 = 8*128)
    int b = swz >> 8;
    int hw0 = (swz & 255) << 6;                   // 64-px window

    const unsigned short* xb = xt + ((size_t)b << 21);
    const float* offp = offset + (size_t)b * (OffC * HWc) + hw0;
    char* vtb = (char*)vt;

    // ---------- Phase 1: gather ----------
    for (int tap = 0; tap < 9; ++tap) {
        if (tid < 256) {                          // one (px, corner) per thread
            int px = tid & 63, cr = tid >> 6;
            float dy = offp[(2 * tap) * HWc + px];
            float dx = offp[(2 * tap + 1) * HWc + px];
            int hh = (hw0 + px) >> 7, ww = (hw0 + px) & 127;
            float ys = (float)(hh - 1 + tap / 3) + dy;
            float xs = (float)(ww - 1 + tap % 3) + dx;
            float y0f = floorf(ys), x0f = floorf(xs);
            float ly = ys - y0f, lx = xs - x0f;
            int y0 = (int)y0f, x0 = (int)x0f;
            int yi = y0 + (cr >> 1), xi = x0 + (cr & 1);
            bool valid = (yi >= 0) && (yi < Hc) && (xi >= 0) && (xi < Wc);
            float wy = (cr >> 1) ? ly : 1.0f - ly;
            float wx = (cr & 1) ? lx : 1.0f - lx;
            int yc = yi < 0 ? 0 : (yi > Hc - 1 ? Hc - 1 : yi);
            int xc = xi < 0 ? 0 : (xi > Wc - 1 ? Wc - 1 : xi);
            cwL[cr][px] = valid ? wy * wx : 0.0f;
            cbL[cr][px] = ((yc << 7) + xc) << 7;  // element offset within batch slice
        }
        __syncthreads();
        // coalesced gather: lanes spread along channels; 2 passes x 32 px
#pragma unroll
        for (int p = 0; p < 2; ++p) {
            int px = (tid >> 4) + (p << 5);       // tid>>4 in 0..31
            int c8 = (tid & 15) << 3;             // 8-ch chunk
            float v[8] = {0.f, 0.f, 0.f, 0.f, 0.f, 0.f, 0.f, 0.f};
#pragma unroll
            for (int cr = 0; cr < 4; ++cr) {
                float wc = cwL[cr][px];
                short8 r = *(const short8*)(xb + cbL[cr][px] + c8);
#pragma unroll
                for (int j = 0; j < 8; ++j)
                    v[j] += wc * bf2f((unsigned short)r[j]);
            }
            short8 pk;
#pragma unroll
            for (int j = 0; j < 8; ++j) pk[j] = (short)f2bf(v[j]);
            *(short8*)(vtb + px * 2320 + tap * 256 + ((tid & 15) << 4)) = pk;
        }
        __syncthreads();                          // protect cwL/cbL reuse; final one guards vt
    }

    // ---------- Phase 2: GEMM (barrier-free) ----------
    int lane = tid & 63, wave = tid >> 6;
    int pxg = wave & 3;                           // px-group 0..3 (16 px each)
    int oh  = wave >> 2;                          // output half 0..1 (4 ot each)

    f32x4 acc[4];
#pragma unroll
    for (int i = 0; i < 4; ++i) acc[i] = (f32x4){0.f, 0.f, 0.f, 0.f};

    int px = (pxg << 4) + (lane & 15);
    char* vrow = vtb + px * 2320 + ((lane >> 4) << 4);

    for (int kstep = 0; kstep < 18; ++kstep) {
        short8 b0 = *(const short8*)(vrow + kstep * 128);        // ks=0
        short8 b1 = *(const short8*)(vrow + kstep * 128 + 64);   // ks=1
        const unsigned short* wk = wtf + (kstep << 13) + ((oh << 3) << 9) + (lane << 3);
#pragma unroll
        for (int ot = 0; ot < 4; ++ot) {
            short8 a0 = *(const short8*)(wk + (ot * 2 + 0) * 512);
            short8 a1 = *(const short8*)(wk + (ot * 2 + 1) * 512);
            acc[ot] = __builtin_amdgcn_mfma_f32_16x16x32_bf16(a0, b0, acc[ot], 0, 0, 0);
            acc[ot] = __builtin_amdgcn_mfma_f32_16x16x32_bf16(a1, b1, acc[ot], 0, 0, 0);
        }
    }

    // epilogue: ReLU + fp32 store. D: col=lane&15 (px), row=(lane>>4)*4+j (o)
    float* ob = out + ((size_t)b << 21) + hw0 + px;
#pragma unroll
    for (int ot = 0; ot < 4; ++ot)
#pragma unroll
        for (int j = 0; j < 4; ++j) {
            int o = ((oh << 2) + ot) * 16 + ((lane >> 4) << 2) + j;
            float v = acc[ot][j];
            ob[o << 14] = v > 0.f ? v : 0.f;
        }
}

extern "C" void kernel_launch(void* const* d_in, const int* in_sizes, int n_in,
                              void* d_out, int out_size, void* d_ws, size_t ws_size,
                              hipStream_t stream) {
    const float* x     = (const float*)d_in[0];
    const float* off   = (const float*)d_in[1];
    const float* w_off = (const float*)d_in[2];
    const float* b_off = (const float*)d_in[3];
    const float* w_def = (const float*)d_in[4];
    float* out = (float*)d_out;

    char* ws = (char*)d_ws;
    float* offset       = (float*)ws;                                  // 4,718,592 B
    unsigned short* xt  = (unsigned short*)(ws + 4718592);             // 16,777,216 B
    unsigned short* wtf = (unsigned short*)(ws + 4718592 + 16777216);  // 294,912 B

    hipLaunchKernelGGL(k_offconv, dim3(256),  dim3(256), 0, stream, off, w_off, b_off, offset);
    hipLaunchKernelGGL(k_xpose,   dim3(1024), dim3(256), 0, stream, x, xt);
    hipLaunchKernelGGL(k_wprep,   dim3(576),  dim3(256), 0, stream, w_def, wtf);
    hipLaunchKernelGGL(k_deform,  dim3(1024), dim3(512), 0, stream, xt, offset, wtf, out);
}